// Round 3
// baseline (3536.447 us; speedup 1.0000x reference)
//
#include <hip/hip_runtime.h>

#define TOKS    65536      // 16 * 4096
#define NCODES  1024
#define REFINE_EPS 0.25f

typedef __attribute__((ext_vector_type(4))) float  f32x4;
typedef __attribute__((ext_vector_type(8))) short  s16x8;
typedef __attribute__((ext_vector_type(4))) unsigned short u16x4;

__device__ __forceinline__ unsigned short f2bf_rne(float f) {
    unsigned int u = __float_as_uint(f);
    u += 0x7fffu + ((u >> 16) & 1u);
    return (unsigned short)(u >> 16);
}

// ---------------------------------------------------------------------------
// Row squared-norm: dst[row] = sum_j src[row][j]^2, 256 cols. One wave/row.
// ---------------------------------------------------------------------------
__global__ __launch_bounds__(256) void rownorm_kernel(
        const float* __restrict__ src, float* __restrict__ dst) {
    int row  = blockIdx.x * 4 + (threadIdx.x >> 6);
    int lane = threadIdx.x & 63;
    float4 v = *(const float4*)(src + (long)row * 256 + lane * 4);
    float s = v.x * v.x + v.y * v.y + v.z * v.z + v.w * v.w;
    #pragma unroll
    for (int off = 32; off; off >>= 1) s += __shfl_xor(s, off, 64);
    if (lane == 0) dst[row] = s;
}

// ---------------------------------------------------------------------------
// codebook fp32 -> bf16 (RNE). 262144 elems, 4/thread.
// ---------------------------------------------------------------------------
__global__ __launch_bounds__(256) void cvt_cb_kernel(
        const float* __restrict__ cb, unsigned short* __restrict__ cb_hi) {
    int i = blockIdx.x * 256 + threadIdx.x;      // 65536 threads
    float4 v = *(const float4*)(cb + (long)i * 4);
    u16x4 o;
    o[0] = f2bf_rne(v.x); o[1] = f2bf_rne(v.y);
    o[2] = f2bf_rne(v.z); o[3] = f2bf_rne(v.w);
    *(u16x4*)(cb_hi + (long)i * 4) = o;
}

// ---------------------------------------------------------------------------
// Tiled fp32 GEMM: C[M,N] = A[M,K] @ B[N,K]^T. 128x128 tile, 8x8 microtile.
// ---------------------------------------------------------------------------
template <int K, int N>
__global__ __launch_bounds__(256, 2) void gemm_kernel(
        const float* __restrict__ A, const float* __restrict__ B,
        float* __restrict__ C) {
    __shared__ float As[64][132];
    __shared__ float Bs[64][132];

    const int m0  = blockIdx.y * 128;
    const int n0  = blockIdx.x * 128;
    const int tid = threadIdx.x;
    const int r   = tid >> 1, h = tid & 1;
    const int ty  = tid >> 4, tx = tid & 15;

    const float* Arow = A + (long)(m0 + r) * K;
    const float* Brow = B + (long)(n0 + r) * K;

    float acc[8][8] = {};

    for (int k0 = 0; k0 < K; k0 += 64) {
        __syncthreads();
        #pragma unroll
        for (int j = 0; j < 8; ++j) {
            int kk = h * 32 + j * 4;
            float4 a = *(const float4*)(Arow + k0 + kk);
            float4 b = *(const float4*)(Brow + k0 + kk);
            As[kk + 0][r] = a.x; As[kk + 1][r] = a.y;
            As[kk + 2][r] = a.z; As[kk + 3][r] = a.w;
            Bs[kk + 0][r] = b.x; Bs[kk + 1][r] = b.y;
            Bs[kk + 2][r] = b.z; Bs[kk + 3][r] = b.w;
        }
        __syncthreads();
        #pragma unroll 4
        for (int k = 0; k < 64; ++k) {
            float4 a0 = *(const float4*)&As[k][ty * 8];
            float4 a1 = *(const float4*)&As[k][ty * 8 + 4];
            float4 b0 = *(const float4*)&Bs[k][tx * 8];
            float4 b1 = *(const float4*)&Bs[k][tx * 8 + 4];
            float av[8] = {a0.x, a0.y, a0.z, a0.w, a1.x, a1.y, a1.z, a1.w};
            float bv[8] = {b0.x, b0.y, b0.z, b0.w, b1.x, b1.y, b1.z, b1.w};
            #pragma unroll
            for (int i = 0; i < 8; ++i)
                #pragma unroll
                for (int j = 0; j < 8; ++j)
                    acc[i][j] += av[i] * bv[j];
        }
    }

    #pragma unroll
    for (int i = 0; i < 8; ++i) {
        float* crow = C + (long)(m0 + ty * 8 + i) * N + n0 + tx * 8;
        *(float4*)crow       = make_float4(acc[i][0], acc[i][1], acc[i][2], acc[i][3]);
        *(float4*)(crow + 4) = make_float4(acc[i][4], acc[i][5], acc[i][6], acc[i][7]);
    }
}

// ---------------------------------------------------------------------------
// MFMA approx-dist + argmin kernel.
// Block = 64 tokens (4 waves x 16). dot ~= z_hi.c_hi + z_lo.c_hi via
// mfma_f32_16x16x32_bf16; A = codes (from LDS), B = tokens (in regs).
// dist = |c|^2 - 2*dot. Tracks best & 2nd-best per token; tokens with
// gap < REFINE_EPS are appended to rlist for exact fp32 rescoring.
// A-frag: m=lane&15, k=(lane>>4)*8+j; B: n=lane&15, same k; D: col(n)=lane&15,
// row(m)=(lane>>4)*4+reg  [per guide §3, m89/m91-verified].
// ---------------------------------------------------------------------------
__global__ __launch_bounds__(256) void dist_mfma_kernel(
        const float* __restrict__ z_e, const unsigned short* __restrict__ cb_hi,
        const float* __restrict__ cnorm,
        int* __restrict__ code_i, float* __restrict__ code_f,
        float* __restrict__ bestd,
        int* __restrict__ rlist, int* __restrict__ rcount) {
    __shared__ unsigned short aLDS[128 * 72];   // 128 codes x 64 k, +8 pad
    __shared__ float cnLDS[1024];

    const int tid  = threadIdx.x;
    const int w    = tid >> 6;
    const int lane = tid & 63;
    const int t0   = blockIdx.x * 64;

    // preload |c|^2
    *(f32x4*)&cnLDS[tid * 4] = *(const f32x4*)(cnorm + tid * 4);

    // B fragments for this wave's 16 tokens, all K=256 (8 k-steps), split hi/lo
    const int kb = (lane >> 4) * 8;
    const float* zrow = z_e + (long)(t0 + w * 16 + (lane & 15)) * 256;
    s16x8 b_hi[8], b_lo[8];
    #pragma unroll
    for (int kq = 0; kq < 8; ++kq) {
        const float* p = zrow + kq * 32 + kb;
        float4 f0 = *(const float4*)p;
        float4 f1 = *(const float4*)(p + 4);
        float fv[8] = {f0.x, f0.y, f0.z, f0.w, f1.x, f1.y, f1.z, f1.w};
        #pragma unroll
        for (int j = 0; j < 8; ++j) {
            unsigned short h = f2bf_rne(fv[j]);
            float hf = __uint_as_float(((unsigned int)h) << 16);
            b_hi[kq][j] = (short)h;
            b_lo[kq][j] = (short)f2bf_rne(fv[j] - hf);
        }
    }

    float best1 = 3.4e38f, best2 = 3.4e38f;
    int   besti = 0;

    for (int ct = 0; ct < 8; ++ct) {
        f32x4 acc[8];
        #pragma unroll
        for (int mt = 0; mt < 8; ++mt) acc[mt] = (f32x4){0.f, 0.f, 0.f, 0.f};

        for (int kc = 0; kc < 4; ++kc) {
            __syncthreads();
            {   // stage 128 codes x 64 k of cb_hi into LDS
                const int cr = tid >> 1, h = tid & 1;
                const unsigned short* src =
                    cb_hi + (long)(ct * 128 + cr) * 256 + kc * 64 + h * 32;
                unsigned short* dst = aLDS + cr * 72 + h * 32;
                #pragma unroll
                for (int j = 0; j < 4; ++j)
                    *(s16x8*)(dst + j * 8) = *(const s16x8*)(src + j * 8);
            }
            __syncthreads();
            #pragma unroll
            for (int mt = 0; mt < 8; ++mt) {
                #pragma unroll
                for (int ks = 0; ks < 2; ++ks) {
                    s16x8 a = *(const s16x8*)&aLDS[(mt * 16 + (lane & 15)) * 72 + ks * 32 + kb];
                    acc[mt] = __builtin_amdgcn_mfma_f32_16x16x32_bf16(
                        a, b_hi[kc * 2 + ks], acc[mt], 0, 0, 0);
                    acc[mt] = __builtin_amdgcn_mfma_f32_16x16x32_bf16(
                        a, b_lo[kc * 2 + ks], acc[mt], 0, 0, 0);
                }
            }
        }

        // epilogue: dist + best/2nd-best update (codes scanned in increasing order)
        const int rbase = (lane >> 4) * 4;
        #pragma unroll
        for (int mt = 0; mt < 8; ++mt) {
            #pragma unroll
            for (int r = 0; r < 4; ++r) {
                int code = ct * 128 + mt * 16 + rbase + r;
                float d = cnLDS[code] - 2.0f * acc[mt][r];
                if (d < best1) { best2 = best1; best1 = d; besti = code; }
                else if (d < best2) { best2 = d; }
            }
        }
    }

    // cross-lane merge: lanes {l, l^16, l^32, l^48} hold same token (col=lane&15)
    #pragma unroll
    for (int off = 16; off <= 32; off <<= 1) {
        float o1 = __shfl_xor(best1, off, 64);
        int   oi = __shfl_xor(besti, off, 64);
        float o2 = __shfl_xor(best2, off, 64);
        if (o1 < best1 || (o1 == best1 && oi < besti)) {
            best2 = fminf(best1, o2); best1 = o1; besti = oi;
        } else {
            best2 = fminf(best2, o1);
        }
    }

    if (lane < 16) {
        int tok = t0 + w * 16 + lane;
        code_i[tok] = besti;
        code_f[tok] = (float)besti;
        bestd[tok]  = best1;
        if (best2 - best1 < REFINE_EPS) {
            int p = atomicAdd(rcount, 1);
            rlist[p] = tok;
        }
    }
}

// ---------------------------------------------------------------------------
// Exact fp32 rescoring of flagged tokens against ALL 1024 codes.
// Fixed grid, device-side loop over chunks of 16 tokens.
// Wave w scans codes [w*256, (w+1)*256); lane owns 4 codes spaced 64.
// ---------------------------------------------------------------------------
__global__ __launch_bounds__(256) void refine_kernel(
        const float* __restrict__ z_e, const float* __restrict__ cb,
        const float* __restrict__ cnorm,
        const int* __restrict__ rlist, const int* __restrict__ rcount,
        int* __restrict__ code_i, float* __restrict__ code_f,
        float* __restrict__ bestd) {
    __shared__ float ze[16][260];
    __shared__ int   toks[16];
    __shared__ float redD[4][16];
    __shared__ int   redI[4][16];

    const int tid  = threadIdx.x;
    const int w    = tid >> 6;
    const int lane = tid & 63;
    const int cnt  = rcount[0];

    for (int chunk = blockIdx.x; chunk * 16 < cnt; chunk += gridDim.x) {
        const int nt = min(16, cnt - chunk * 16);
        __syncthreads();
        {   // stage z_e rows of gathered tokens: 16 threads per token
            int ti = tid >> 4, col = tid & 15;
            if (ti < nt) {
                int tk = rlist[chunk * 16 + ti];
                if (col == 0) toks[ti] = tk;
                const float* zr = z_e + (long)tk * 256;
                #pragma unroll
                for (int j = 0; j < 4; ++j)
                    *(f32x4*)&ze[ti][col * 16 + j * 4] =
                        *(const f32x4*)(zr + col * 16 + j * 4);
            }
        }
        __syncthreads();

        float acc[4][16] = {};
        for (int k4 = 0; k4 < 64; ++k4) {
            float4 cv[4];
            #pragma unroll
            for (int c = 0; c < 4; ++c)
                cv[c] = *(const float4*)(cb + (long)(w * 256 + c * 64 + lane) * 256 + k4 * 4);
            #pragma unroll
            for (int t = 0; t < 16; ++t) {
                float4 zv = *(const float4*)&ze[t][k4 * 4];
                #pragma unroll
                for (int c = 0; c < 4; ++c) {
                    acc[c][t] += zv.x * cv[c].x + zv.y * cv[c].y
                               + zv.z * cv[c].z + zv.w * cv[c].w;
                }
            }
        }

        float cn[4];
        #pragma unroll
        for (int c = 0; c < 4; ++c) cn[c] = cnorm[w * 256 + c * 64 + lane];

        #pragma unroll
        for (int t = 0; t < 16; ++t) {
            float d = cn[0] - 2.0f * acc[0][t];
            int idx = w * 256 + lane;
            #pragma unroll
            for (int c = 1; c < 4; ++c) {
                float dc = cn[c] - 2.0f * acc[c][t];
                if (dc < d) { d = dc; idx = w * 256 + c * 64 + lane; }
            }
            #pragma unroll
            for (int off = 32; off; off >>= 1) {
                float od = __shfl_xor(d, off, 64);
                int   oi = __shfl_xor(idx, off, 64);
                if (od < d || (od == d && oi < idx)) { d = od; idx = oi; }
            }
            if (lane == 0) { redD[w][t] = d; redI[w][t] = idx; }
        }
        __syncthreads();
        if (tid < nt) {
            float bd = redD[0][tid]; int bi = redI[0][tid];
            #pragma unroll
            for (int wv = 1; wv < 4; ++wv) {
                if (redD[wv][tid] < bd) { bd = redD[wv][tid]; bi = redI[wv][tid]; }
            }
            int tk = toks[tid];
            code_i[tk] = bi;
            code_f[tk] = (float)bi;
            bestd[tk]  = bd;
        }
    }
}

// ---------------------------------------------------------------------------
// z_out[tok] = U[code[tok]]  (U = codebook @ w_up^T, [1024,512] fp32)
// ---------------------------------------------------------------------------
__global__ __launch_bounds__(256) void gather_kernel(
        const float4* __restrict__ U4, const int* __restrict__ code_i,
        float4* __restrict__ out4) {
    int i = blockIdx.x * 256 + threadIdx.x;     // 2097152 threads, 4 f4 each
    #pragma unroll
    for (int r = 0; r < 4; ++r) {
        int idx = i + r * 2097152;
        int tok = idx >> 7;
        int c   = idx & 127;
        out4[idx] = U4[(long)code_i[tok] * 128 + c];
    }
}

// ---------------------------------------------------------------------------
// Per-batch loss: sum(bestd + znorm) over 4096 tokens, scale, write both.
// ---------------------------------------------------------------------------
__global__ __launch_bounds__(256) void loss_kernel(
        const float* __restrict__ bestd, const float* __restrict__ znorm,
        float* __restrict__ out_losses) {
    __shared__ float red[4];
    const int b = blockIdx.x;
    const int tid = threadIdx.x, lane = tid & 63;
    float s = 0.f;
    #pragma unroll
    for (int j = 0; j < 16; ++j) {
        int t = b * 4096 + j * 256 + tid;
        s += bestd[t] + znorm[t];
    }
    #pragma unroll
    for (int off = 32; off; off >>= 1) s += __shfl_xor(s, off, 64);
    if (lane == 0) red[tid >> 6] = s;
    __syncthreads();
    if (tid == 0) {
        float v = (red[0] + red[1] + red[2] + red[3]) * (1.0f / 1048576.0f);
        out_losses[b]      = v;
        out_losses[16 + b] = v;
    }
}

// ---------------------------------------------------------------------------
extern "C" void kernel_launch(void* const* d_in, const int* in_sizes, int n_in,
                              void* d_out, int out_size, void* d_ws, size_t ws_size,
                              hipStream_t stream) {
    const float* z      = (const float*)d_in[0];  // [16,4096,512]
    const float* cb     = (const float*)d_in[1];  // [1024,256]
    const float* w_down = (const float*)d_in[2];  // [256,512]
    const float* w_up   = (const float*)d_in[3];  // [512,256]

    float* out        = (float*)d_out;
    float* z_out      = out;                      // 33554432 floats
    float* out_losses = out + 33554432;           // 32 floats
    float* code_f     = out + 33554464;           // 65536 floats

    char* ws = (char*)d_ws;
    float*          z_e    = (float*)ws;                          // 64 MiB
    unsigned short* cb_hi  = (unsigned short*)(ws + 67108864);    // 512 KiB
    float*          U      = (float*)(ws + 67633152);             // 2 MiB
    float*          cnorm  = (float*)(ws + 69730304);             // 4 KiB
    float*          znorm  = (float*)(ws + 69734400);             // 256 KiB
    float*          bestd  = (float*)(ws + 69996544);             // 256 KiB
    int*            code_i = (int*)  (ws + 70258688);             // 256 KiB
    int*            rlist  = (int*)  (ws + 70520832);             // 256 KiB
    int*            rcount = (int*)  (ws + 70782976);             // 64 B

    hipMemsetAsync(rcount, 0, 64, stream);

    // codebook prep: bf16 copy + row norms
    cvt_cb_kernel<<<256, 256, 0, stream>>>(cb, cb_hi);
    rownorm_kernel<<<NCODES / 4, 256, 0, stream>>>(cb, cnorm);

    // GEMM1 (fp32): z_e = z @ w_down^T   [65536,512]x[512,256]
    gemm_kernel<512, 256><<<dim3(256 / 128, TOKS / 128), 256, 0, stream>>>(
        z, w_down, z_e);

    // |z_e|^2 per token
    rownorm_kernel<<<TOKS / 4, 256, 0, stream>>>(z_e, znorm);

    // approx distances (split-bf16 MFMA) + argmin + refine-list
    dist_mfma_kernel<<<TOKS / 64, 256, 0, stream>>>(
        z_e, cb_hi, cnorm, code_i, code_f, bestd, rlist, rcount);

    // exact fp32 rescoring of near-tie tokens
    refine_kernel<<<128, 256, 0, stream>>>(
        z_e, cb, cnorm, rlist, rcount, code_i, code_f, bestd);

    // U = codebook @ w_up^T  [1024,256]x[256,512] (fp32)
    gemm_kernel<256, 512><<<dim3(512 / 128, NCODES / 128), 256, 0, stream>>>(
        cb, w_up, U);

    // z_out = U[code]
    gather_kernel<<<8192, 256, 0, stream>>>(
        (const float4*)U, code_i, (float4*)z_out);

    // losses
    loss_kernel<<<16, 256, 0, stream>>>(bestd, znorm, out_losses);
}